// Round 4
// baseline (739.191 us; speedup 1.0000x reference)
//
#include <hip/hip_runtime.h>
#include <cfloat>
#include <cstdint>

// Problem constants
#define NROWS 131072
#define DIMD  128
#define KCODE 1024
#define MARGIN 0.045f  // f16 single-pass gap error sigma ~9.6e-3 -> ~4.7 sigma

typedef __attribute__((ext_vector_type(8))) _Float16 half8;  // 8 f16 = 4 VGPRs
typedef __attribute__((ext_vector_type(4))) float f32x4;

union U4H8 { uint4 u; half8 h; };

// ---- workspace layout (bytes); total ~3.23 MB ----
#define WS_REFINE_CNT 0         // int
#define WS_LOSS       8         // float (loss accumulator, zeroed by memset)
#define WS_COUNTS     16        // int[1024]
#define WS_SUMS       4608      // float[K*D] = 512 KB (layout [k][d])
#define WS_OFFSETS    528896    // int[1024]
#define WS_CURSOR     532992    // int[1024]
#define WS_E2         537088    // float[1024]
#define WS_ZERO_BYTES 541184    // memset [0, WS_ZERO_BYTES) — covers e2 too
#define WS_ET         541184    // float[K*D] (ET[k][d])
#define WS_BHI        1065472   // uint4[16384] = 256 KB (f16 B fragments)
#define WS_BLO        1327616   // uint4[16384] (unused; layout stability)
#define WS_IDX        1589760   // int[N]
#define WS_ROWLIST    2114048   // int[N]
#define WS_REFINE     2638336   // int[N]
#define WS_PARTIALS   3162624   // float[16384] (unused; layout stability)
// end: 3228160 bytes

// ---- output offsets (in floats), reference return order ----
#define OUT_QST  ((size_t)0)
#define OUT_EMB  ((size_t)NROWS * DIMD)
#define OUT_CNT  (OUT_EMB + (size_t)DIMD * KCODE)
#define OUT_ES   (OUT_CNT + KCODE)
#define OUT_LOSS (OUT_ES + (size_t)DIMD * KCODE)

__device__ __forceinline__ unsigned f16pair(float a, float b) {
    union { _Float16 h[2]; unsigned u; } p;
    p.h[0] = (_Float16)a;
    p.h[1] = (_Float16)b;
    return p.u;
}

// ============================================================
// Fused prep: one pass over E (each thread reads 8 elements of E exactly
// once) producing (1) Bh MFMA B-fragments (f16), (2) ET[k][d] transpose,
// (3) e2[k] = sum_d E[d][k]^2 via atomics (16 contributing threads per k).
// Replaces 3 kernels (prep_e2 / transpose / prep_bfrag).
// Fragment fi = (NB*4 + t)*64 + lane; lane holds B[k = t*32 + (lane>>4)*8 + j]
// [n = NB*16 + (lane&15)], j = 0..7, value = f16(E[k][n]) (k is the d-dim).
__global__ void vq_prep(const float* __restrict__ E, uint4* __restrict__ Bh,
                        float* __restrict__ ET, float* __restrict__ e2) {
    int gid = blockIdx.x * 256 + threadIdx.x;   // 0..16383 == fi
    int l = gid & 63;
    int t = (gid >> 6) & 3;
    int NB = gid >> 8;
    int n = NB * 16 + (l & 15);
    int k0 = t * 32 + (l >> 4) * 8;
    float v[8];
    float ss = 0.f;
    #pragma unroll
    for (int j = 0; j < 8; ++j) {
        v[j] = E[(size_t)(k0 + j) * KCODE + n];
        ss = fmaf(v[j], v[j], ss);
    }
    Bh[gid] = make_uint4(f16pair(v[0], v[1]), f16pair(v[2], v[3]),
                         f16pair(v[4], v[5]), f16pair(v[6], v[7]));
    float4* et4 = (float4*)(ET + (size_t)n * DIMD + k0);
    et4[0] = make_float4(v[0], v[1], v[2], v[3]);
    et4[1] = make_float4(v[4], v[5], v[6], v[7]);
    atomicAdd(&e2[n], ss);
}

// ============================================================
// Main kernel: per-row argmin_k ( ||e_k||^2 - 2 x.e_k ) via SINGLE-PASS f16
// MFMA. 512 threads = 8 waves; wave w: row-group g = w&3 (64 rows),
// K-half h = w>>2 (512 codes). In-block K-split doubles waves/CU (8 -> 16)
// at constant total L2 B-traffic — the round-3 counters showed the kernel
// latency-bound at 2 waves/SIMD (MfmaUtil 12%, VALUBusy 35%, occ 20%).
// Halves merged via LDS, then quad shfl merge. No K-loop barriers; B
// register double-buffered straight from global (B is L2-resident).

#define LOADB(bARR, ev_, nb_)                                     \
  { _Pragma("unroll")                                             \
    for (int t_ = 0; t_ < 4; ++t_)                                \
      bARR[t_] = Bh[((nb_) * 4 + t_) * 64 + l];                   \
    ev_ = e2[(nb_) * 16 + m]; }

#define COMPUTE_NB(nb_, bARR, ev_)                                           \
  {                                                                          \
    f32x4 acc[4];                                                            \
    _Pragma("unroll")                                                        \
    for (int mt_ = 0; mt_ < 4; ++mt_) acc[mt_] = (f32x4){0.f,0.f,0.f,0.f};   \
    _Pragma("unroll")                                                        \
    for (int t_ = 0; t_ < 4; ++t_) {                                         \
      U4H8 bh_; bh_.u = bARR[t_];                                            \
      _Pragma("unroll")                                                      \
      for (int mt_ = 0; mt_ < 4; ++mt_)                                      \
        acc[mt_] = __builtin_amdgcn_mfma_f32_16x16x32_f16(ah[mt_][t_], bh_.h,\
                                                          acc[mt_], 0, 0, 0);\
    }                                                                        \
    int col_ = (nb_) * 16 + m;                                               \
    _Pragma("unroll")                                                        \
    for (int mt_ = 0; mt_ < 4; ++mt_)                                        \
      _Pragma("unroll")                                                      \
      for (int r_ = 0; r_ < 4; ++r_) {                                       \
        float s_ = fmaf(-2.0f, acc[mt_][r_], ev_);                           \
        if (s_ < m1[mt_][r_]) {                                              \
          m2[mt_][r_] = m1[mt_][r_]; m1[mt_][r_] = s_; i1[mt_][r_] = col_;   \
        } else if (s_ < m2[mt_][r_]) { m2[mt_][r_] = s_; }                   \
      }                                                                      \
  }

__global__ __launch_bounds__(512, 4) void vq_argmin_mfma(
        const float* __restrict__ x, const uint4* __restrict__ Bh,
        const float* __restrict__ e2,
        int* __restrict__ idx, int* __restrict__ counts,
        int* __restrict__ refine_rows, int* __restrict__ refine_cnt) {

    __shared__ float ldsM1[4][16][64];   // 16 KB
    __shared__ float ldsM2[4][16][64];   // 16 KB
    __shared__ int   ldsI1[4][16][64];   // 16 KB
    __shared__ int   hist[KCODE];        // 4 KB

    const int tid = threadIdx.x;
    const int w = tid >> 6, l = tid & 63;
    const int g = w & 3, h = w >> 2;
    const int m = l & 15, q = l >> 4;
    const int rw = blockIdx.x * 256 + g * 64;
    const int base = h * 32;             // this wave's nb range [base, base+32)

    // B prefetch prologue (in flight while the A-phase loads/converts)
    uint4 bA[4], bB[4];
    float evA, evB;
    LOADB(bA, evA, base + 0);
    LOADB(bB, evB, base + 1);

    // ---------- A-phase: f16 A-fragments straight from global ----------
    // lane (m,q) of m-tile mt holds x[rw+mt*16+m][t*32 + q*8 + j], j=0..7
    const float4* x4 = (const float4*)x;
    half8 ah[4][4];                 // [m-tile][k-tile]
    #pragma unroll
    for (int mt = 0; mt < 4; ++mt) {
        int row = rw + mt * 16 + m;
        #pragma unroll
        for (int t = 0; t < 4; ++t) {
            int c4 = t * 8 + q * 2;
            float4 va = x4[(size_t)row * 32 + c4];
            float4 vb = x4[(size_t)row * 32 + c4 + 1];
            half8 hh;
            hh[0] = (_Float16)va.x; hh[1] = (_Float16)va.y;
            hh[2] = (_Float16)va.z; hh[3] = (_Float16)va.w;
            hh[4] = (_Float16)vb.x; hh[5] = (_Float16)vb.y;
            hh[6] = (_Float16)vb.z; hh[7] = (_Float16)vb.w;
            ah[mt][t] = hh;
        }
    }

    float m1[4][4], m2[4][4];
    int i1[4][4];
    #pragma unroll
    for (int a = 0; a < 4; ++a)
        #pragma unroll
        for (int r = 0; r < 4; ++r) { m1[a][r] = FLT_MAX; m2[a][r] = FLT_MAX; i1[a][r] = 0; }

    // ---------- K-loop over this wave's 32 n-blocks, barrier-free ----------
    for (int i2 = 0; i2 < 32; i2 += 2) {
        int nb = base + i2;
        COMPUTE_NB(nb, bA, evA);
        { int p = (i2 + 2 < 32) ? nb + 2 : base + 30; LOADB(bA, evA, p); }
        COMPUTE_NB(nb + 1, bB, evB);
        { int p = (i2 + 3 < 32) ? nb + 3 : base + 31; LOADB(bB, evB, p); }
    }

    // ---------- merge the two K-halves through LDS ----------
    for (int i = tid; i < KCODE; i += 512) hist[i] = 0;
    if (h == 1) {
        #pragma unroll
        for (int mt = 0; mt < 4; ++mt)
            #pragma unroll
            for (int r = 0; r < 4; ++r) {
                ldsM1[g][mt * 4 + r][l] = m1[mt][r];
                ldsM2[g][mt * 4 + r][l] = m2[mt][r];
                ldsI1[g][mt * 4 + r][l] = i1[mt][r];
            }
    }
    __syncthreads();
    if (h == 0) {
        #pragma unroll
        for (int mt = 0; mt < 4; ++mt)
            #pragma unroll
            for (int r = 0; r < 4; ++r) {
                float o1 = ldsM1[g][mt * 4 + r][l];
                float o2 = ldsM2[g][mt * 4 + r][l];
                int oi = ldsI1[g][mt * 4 + r][l];
                float hi = fmaxf(m1[mt][r], o1);
                float n2 = fminf(fminf(m2[mt][r], o2), hi);
                // o comes from the upper K-half: oi > i1 always, so strict <
                bool take = (o1 < m1[mt][r]);
                m1[mt][r] = fminf(m1[mt][r], o1);
                i1[mt][r] = take ? oi : i1[mt][r];
                m2[mt][r] = n2;
            }
    }

    // ---------- merge across the 16 lanes of each quad ----------
    #pragma unroll
    for (int mt = 0; mt < 4; ++mt)
        #pragma unroll
        for (int r = 0; r < 4; ++r) {
            float a1 = m1[mt][r], a2 = m2[mt][r];
            int ai = i1[mt][r];
            #pragma unroll
            for (int off = 1; off < 16; off <<= 1) {
                float o1 = __shfl_xor(a1, off, 64);
                float o2 = __shfl_xor(a2, off, 64);
                int oi = __shfl_xor(ai, off, 64);
                float hi = fmaxf(a1, o1);
                float n2 = fminf(fminf(a2, o2), hi);
                bool take = (o1 < a1) || (o1 == a1 && oi < ai);  // first-index ties
                a1 = fminf(a1, o1);
                ai = take ? oi : ai;
                a2 = n2;
            }
            m1[mt][r] = a1; m2[mt][r] = a2; i1[mt][r] = ai;
        }

    // ---------- write idx, LDS-aggregated histogram, refine list ----------
    if (h == 0 && m == 0) {   // 4 representative lanes per h=0 wave
        #pragma unroll
        for (int mt = 0; mt < 4; ++mt)
            #pragma unroll
            for (int r = 0; r < 4; ++r) {
                int row = rw + mt * 16 + q * 4 + r;
                int bi = i1[mt][r];
                idx[row] = bi;
                atomicAdd(&hist[bi], 1);
                if (!(m2[mt][r] - m1[mt][r] > MARGIN)) {
                    int pos = atomicAdd(refine_cnt, 1);
                    refine_rows[pos] = row;
                }
            }
    }
    __syncthreads();
    for (int i = tid; i < KCODE; i += 512) {
        int hh = hist[i];
        if (hh) atomicAdd(&counts[i], hh);
    }
}

// ============================================================
// Exact re-resolution of ambiguous rows, fp32 expanded form (same arithmetic
// structure as the reference: e2 - 2*x.e, error ~1e-5). 16 rows per batch;
// E loads batched 16-wide so 16 independent loads are in flight over 256
// FMAs (round-3 version was load-latency-bound on the d-loop). Grid 512:
// one sweep covers 8192 rows.
#define RROWS 16
__global__ __launch_bounds__(256, 2) void vq_refine(
        const float* __restrict__ x, const float* __restrict__ E,
        const float* __restrict__ e2,
        const int* __restrict__ refine_rows, const int* __restrict__ refine_cnt,
        int* __restrict__ idx, int* __restrict__ counts) {
    __shared__ float xs[RROWS][DIMD];   // 8 KB
    __shared__ float rv[4][RROWS];
    __shared__ int   ri_[4][RROWS];
    const int cnt = *refine_cnt;
    const int tid = threadIdx.x;
    const int wave = tid >> 6, lane = tid & 63;

    for (int bb = blockIdx.x * RROWS; bb < cnt; bb += gridDim.x * RROWS) {
        __syncthreads();   // previous iteration done with LDS
        for (int i = tid; i < RROWS * DIMD; i += 256) {
            int r = i >> 7, d = i & 127;
            int wl = bb + r;
            if (wl >= cnt) wl = cnt - 1;        // clamp (dup compute, guarded write)
            xs[r][d] = x[(size_t)refine_rows[wl] * DIMD + d];
        }
        __syncthreads();

        float best[RROWS]; int bi[RROWS];
        #pragma unroll
        for (int r = 0; r < RROWS; ++r) { best[r] = FLT_MAX; bi[r] = 0; }

        for (int kc = 0; kc < KCODE / 256; ++kc) {
            int k = kc * 256 + tid;
            float acc[RROWS];
            #pragma unroll
            for (int r = 0; r < RROWS; ++r) acc[r] = 0.f;
            for (int d0 = 0; d0 < DIMD; d0 += 16) {
                float ev[16];
                #pragma unroll
                for (int dd = 0; dd < 16; ++dd)
                    ev[dd] = E[(size_t)(d0 + dd) * KCODE + k];   // 16 loads in flight
                #pragma unroll
                for (int dd = 0; dd < 16; ++dd)
                    #pragma unroll
                    for (int r = 0; r < RROWS; ++r)
                        acc[r] = fmaf(xs[r][d0 + dd], ev[dd], acc[r]);
            }
            float e2k = e2[k];
            #pragma unroll
            for (int r = 0; r < RROWS; ++r) {
                float s = fmaf(-2.0f, acc[r], e2k);
                if (s < best[r]) { best[r] = s; bi[r] = k; }   // k ascending: first-min
            }
        }

        // reduce over 64 lanes, then 4 waves; ties -> lowest index
        #pragma unroll
        for (int r = 0; r < RROWS; ++r) {
            float b = best[r]; int j = bi[r];
            #pragma unroll
            for (int off = 1; off < 64; off <<= 1) {
                float ob = __shfl_xor(b, off, 64);
                int oj = __shfl_xor(j, off, 64);
                if (ob < b || (ob == b && oj < j)) { b = ob; j = oj; }
            }
            if (lane == 0) { rv[wave][r] = b; ri_[wave][r] = j; }
        }
        __syncthreads();
        if (tid < RROWS) {
            int r = tid;
            float b = rv[0][r]; int j = ri_[0][r];
            #pragma unroll
            for (int wv = 1; wv < 4; ++wv) {
                float ob = rv[wv][r]; int oj = ri_[wv][r];
                if (ob < b || (ob == b && oj < j)) { b = ob; j = oj; }
            }
            int wl = bb + r;
            if (wl < cnt) {
                int n = refine_rows[wl];
                int oldk = idx[n];
                if (j != oldk) {
                    idx[n] = j;
                    atomicSub(&counts[oldk], 1);
                    atomicAdd(&counts[j], 1);
                }
            }
        }
    }
}

// ============================================================
__global__ void vq_scan(const int* __restrict__ counts, int* __restrict__ offsets,
                        int* __restrict__ cursor) {
    __shared__ int s[KCODE];
    int t = threadIdx.x;
    int c = counts[t];
    s[t] = c;
    __syncthreads();
    for (int off = 1; off < KCODE; off <<= 1) {
        int v = (t >= off) ? s[t - off] : 0;
        __syncthreads();
        s[t] += v;
        __syncthreads();
    }
    int excl = s[t] - c;
    offsets[t] = excl;
    cursor[t] = excl;
}

// LDS-aggregated bucket fill (kills same-address global atomic chains)
__global__ void vq_fill(const int* __restrict__ idx, int* __restrict__ cursor,
                        int* __restrict__ rowlist) {
    __shared__ int hcnt[KCODE];
    __shared__ int hbase[KCODE];
    int tid = threadIdx.x;
    for (int i = tid; i < KCODE; i += 256) hcnt[i] = 0;
    __syncthreads();
    int n = blockIdx.x * 256 + tid;
    int k = idx[n];
    int lrank = atomicAdd(&hcnt[k], 1);
    __syncthreads();
    for (int i = tid; i < KCODE; i += 256) {
        int h = hcnt[i];
        if (h) hbase[i] = atomicAdd(&cursor[i], h);
    }
    __syncthreads();
    rowlist[hbase[k] + lrank] = n;
}

// Balanced segment-sum: each block scans 128 rowlist entries (sorted by code),
// accumulates per-thread-d partials, flushes at code boundaries via atomics.
__global__ void vq_chunksum(const float* __restrict__ x,
                            const int* __restrict__ rowlist,
                            const int* __restrict__ idx,
                            float* __restrict__ sums) {
    __shared__ int rl[128];
    __shared__ int kk[128];
    int tid = threadIdx.x;   // 128 threads, tid == d
    int base = blockIdx.x * 128;
    int r = rowlist[base + tid];
    rl[tid] = r;
    kk[tid] = idx[r];
    __syncthreads();
    float s = 0.f;
    int kprev = kk[0];
    #pragma unroll 4
    for (int j = 0; j < 128; ++j) {
        int kj = kk[j];
        if (kj != kprev) {
            atomicAdd(&sums[(size_t)kprev * DIMD + tid], s);
            s = 0.f;
            kprev = kj;
        }
        s += x[(size_t)rl[j] * DIMD + tid];
    }
    atomicAdd(&sums[(size_t)kprev * DIMD + tid], s);
}

// q_st = x + (quantized - x) (replicating reference fp32 rounding) + loss
// accumulated via one fp32 atomic per block into the workspace.
__global__ void vq_quantize_loss(const float* __restrict__ x,
                                 const float* __restrict__ ET,
                                 const int* __restrict__ idx,
                                 float* __restrict__ out,
                                 float* __restrict__ loss_acc) {
    size_t gid = (size_t)blockIdx.x * 256 + threadIdx.x;
    size_t base = gid * 4;
    int n = (int)(base >> 7);
    int d = (int)(base & 127);
    int k = idx[n];
    float4 xv = *(const float4*)(x + base);
    float4 qv = *(const float4*)(ET + (size_t)k * DIMD + d);
    float t0 = qv.x - xv.x, t1 = qv.y - xv.y, t2 = qv.z - xv.z, t3 = qv.w - xv.w;
    float4 o;
    o.x = xv.x + t0; o.y = xv.y + t1; o.z = xv.z + t2; o.w = xv.w + t3;
    *(float4*)(out + OUT_QST + base) = o;
    float partial = t0 * t0 + t1 * t1 + t2 * t2 + t3 * t3;
    #pragma unroll
    for (int off = 32; off > 0; off >>= 1)
        partial += __shfl_down(partial, off);
    __shared__ float wsum[4];
    int wave = threadIdx.x >> 6;
    if ((threadIdx.x & 63) == 0) wsum[wave] = partial;
    __syncthreads();
    if (threadIdx.x == 0)
        atomicAdd(loss_acc, wsum[0] + wsum[1] + wsum[2] + wsum[3]);
}

// EMA outputs from sums + counts; thread 0 also finalizes the loss scalar
// (launched after vq_quantize_loss).
__global__ void vq_finalize_emb(const int* __restrict__ counts,
                                const float* __restrict__ sums,
                                const float* __restrict__ emc,
                                const float* __restrict__ es,
                                const float* __restrict__ loss_acc,
                                float* __restrict__ out) {
    int gid = blockIdx.x * 256 + threadIdx.x;   // 131072
    int k = gid & (KCODE - 1), d = gid >> 10;
    float cnt = (float)counts[k];
    float ecn = fmaf(0.85f, cnt, 0.15f * emc[k]);
    float esn = fmaf(0.85f, sums[(size_t)k * DIMD + d], 0.15f * es[(size_t)d * KCODE + k]);
    out[OUT_ES + (size_t)d * KCODE + k] = esn;
    out[OUT_EMB + (size_t)d * KCODE + k] = esn / fmaxf(ecn, 1e-5f);
    if (d == 0) out[OUT_CNT + k] = ecn;
    if (gid == 0)
        out[OUT_LOSS] = *loss_acc / ((float)NROWS * (float)DIMD);  // BETA = 1
}

// ============================================================
extern "C" void kernel_launch(void* const* d_in, const int* in_sizes, int n_in,
                              void* d_out, int out_size, void* d_ws, size_t ws_size,
                              hipStream_t stream) {
    const float* x   = (const float*)d_in[0];
    const float* E   = (const float*)d_in[1];
    const float* emc = (const float*)d_in[2];
    const float* es  = (const float*)d_in[3];
    float* out = (float*)d_out;
    char* ws = (char*)d_ws;

    int*    refine_cnt  = (int*)(ws + WS_REFINE_CNT);
    float*  loss_acc    = (float*)(ws + WS_LOSS);
    int*    counts      = (int*)(ws + WS_COUNTS);
    float*  sums        = (float*)(ws + WS_SUMS);
    int*    offsets     = (int*)(ws + WS_OFFSETS);
    int*    cursor      = (int*)(ws + WS_CURSOR);
    float*  e2          = (float*)(ws + WS_E2);
    float*  ET          = (float*)(ws + WS_ET);
    uint4*  Bh          = (uint4*)(ws + WS_BHI);
    int*    idx         = (int*)(ws + WS_IDX);
    int*    rowlist     = (int*)(ws + WS_ROWLIST);
    int*    refine_rows = (int*)(ws + WS_REFINE);

    // zero: refine counter, loss, counts, sums, offsets, cursor, e2
    hipMemsetAsync(ws, 0, WS_ZERO_BYTES, stream);

    vq_prep<<<64, 256, 0, stream>>>(E, Bh, ET, e2);
    vq_argmin_mfma<<<NROWS / 256, 512, 0, stream>>>(x, Bh, e2, idx, counts,
                                                    refine_rows, refine_cnt);
    vq_refine<<<512, 256, 0, stream>>>(x, E, e2, refine_rows, refine_cnt, idx, counts);
    vq_scan<<<1, KCODE, 0, stream>>>(counts, offsets, cursor);
    vq_fill<<<NROWS / 256, 256, 0, stream>>>(idx, cursor, rowlist);
    vq_chunksum<<<NROWS / 128, 128, 0, stream>>>(x, rowlist, idx, sums);
    vq_quantize_loss<<<(NROWS * (size_t)DIMD) / (256 * 4), 256, 0, stream>>>(x, ET, idx, out, loss_acc);
    vq_finalize_emb<<<(DIMD * KCODE) / 256, 256, 0, stream>>>(counts, sums, emc, es, loss_acc, out);
}

// Round 5
// 370.692 us; speedup vs baseline: 1.9941x; 1.9941x over previous
//
#include <hip/hip_runtime.h>
#include <cfloat>
#include <cstdint>

// Problem constants
#define NROWS 131072
#define DIMD  128
#define KCODE 1024
#define MARGIN 0.045f  // f16 single-pass gap error sigma ~9.6e-3 -> ~4.7 sigma

typedef __attribute__((ext_vector_type(8))) _Float16 half8;  // 8 f16 = 4 VGPRs
typedef __attribute__((ext_vector_type(4))) float f32x4;

union U4H8 { uint4 u; half8 h; };

// ---- workspace layout (bytes); total ~3.23 MB ----
#define WS_REFINE_CNT 0         // int
#define WS_LOSS       8         // float (unused slot; layout stability)
#define WS_COUNTS     16        // int[1024]
#define WS_SUMS       4608      // float[K*D] = 512 KB (layout [k][d])
#define WS_LPART      528896    // float[256] loss partial slots (zeroed; was offsets)
#define WS_CURSOR     532992    // int[1024]
#define WS_E2         537088    // float[1024]
#define WS_ZERO_BYTES 541184    // memset [0, WS_ZERO_BYTES) — covers e2 too
#define WS_ET         541184    // float[K*D] (ET[k][d])
#define WS_BHI        1065472   // uint4[16384] = 256 KB (f16 B fragments)
#define WS_BLO        1327616   // uint4[16384] (unused; layout stability)
#define WS_IDX        1589760   // int[N]
#define WS_ROWLIST    2114048   // int[N]
#define WS_REFINE     2638336   // int[N]
#define WS_PARTIALS   3162624   // float[16384] (unused; layout stability)
// end: 3228160 bytes

// ---- output offsets (in floats), reference return order ----
#define OUT_QST  ((size_t)0)
#define OUT_EMB  ((size_t)NROWS * DIMD)
#define OUT_CNT  (OUT_EMB + (size_t)DIMD * KCODE)
#define OUT_ES   (OUT_CNT + KCODE)
#define OUT_LOSS (OUT_ES + (size_t)DIMD * KCODE)

__device__ __forceinline__ unsigned f16pair(float a, float b) {
    union { _Float16 h[2]; unsigned u; } p;
    p.h[0] = (_Float16)a;
    p.h[1] = (_Float16)b;
    return p.u;
}

// ============================================================
// Fused prep: one pass over E (each thread reads 8 elements of E exactly
// once) producing (1) Bh MFMA B-fragments (f16), (2) ET[k][d] transpose,
// (3) e2[k] = sum_d E[d][k]^2 via atomics (16 contributing threads per k).
__global__ void vq_prep(const float* __restrict__ E, uint4* __restrict__ Bh,
                        float* __restrict__ ET, float* __restrict__ e2) {
    int gid = blockIdx.x * 256 + threadIdx.x;   // 0..16383 == fi
    int l = gid & 63;
    int t = (gid >> 6) & 3;
    int NB = gid >> 8;
    int n = NB * 16 + (l & 15);
    int k0 = t * 32 + (l >> 4) * 8;
    float v[8];
    float ss = 0.f;
    #pragma unroll
    for (int j = 0; j < 8; ++j) {
        v[j] = E[(size_t)(k0 + j) * KCODE + n];
        ss = fmaf(v[j], v[j], ss);
    }
    Bh[gid] = make_uint4(f16pair(v[0], v[1]), f16pair(v[2], v[3]),
                         f16pair(v[4], v[5]), f16pair(v[6], v[7]));
    float4* et4 = (float4*)(ET + (size_t)n * DIMD + k0);
    et4[0] = make_float4(v[0], v[1], v[2], v[3]);
    et4[1] = make_float4(v[4], v[5], v[6], v[7]);
    atomicAdd(&e2[n], ss);
}

// ============================================================
// Main kernel: per-row argmin_k ( ||e_k||^2 - 2 x.e_k ) via SINGLE-PASS f16
// MFMA. ROW-SPLIT for occupancy: 256 threads = 4 waves, each wave owns
// 32 rows (2 m-tiles of 16), grid = NROWS/128 = 1024 blocks. Lower
// per-thread state (~70 VGPR vs 92) + doubled grid -> 4 blocks/CU =
// 16 waves/CU (round 3 was grid-limited to 8 waves/CU, latency-bound).
// NOTE round-4 lesson: do NOT force waves/EU via launch_bounds — (512,4)
// capped VGPR at 64 and spilled (FETCH 34->685 MB). (256,2) = cap 256.
// No K-loop barriers; B register double-buffered straight from global
// (B is 256 KB, L2-resident; 4 waves share lines through L1).

#define LOADB(bARR, ev_, nb_)                                     \
  { _Pragma("unroll")                                             \
    for (int t_ = 0; t_ < 4; ++t_)                                \
      bARR[t_] = Bh[((nb_) * 4 + t_) * 64 + l];                   \
    ev_ = e2[(nb_) * 16 + m]; }

#define COMPUTE_NB(nb_, bARR, ev_)                                           \
  {                                                                          \
    f32x4 acc[2];                                                            \
    _Pragma("unroll")                                                        \
    for (int mt_ = 0; mt_ < 2; ++mt_) acc[mt_] = (f32x4){0.f,0.f,0.f,0.f};   \
    _Pragma("unroll")                                                        \
    for (int t_ = 0; t_ < 4; ++t_) {                                         \
      U4H8 bh_; bh_.u = bARR[t_];                                            \
      _Pragma("unroll")                                                      \
      for (int mt_ = 0; mt_ < 2; ++mt_)                                      \
        acc[mt_] = __builtin_amdgcn_mfma_f32_16x16x32_f16(ah[mt_][t_], bh_.h,\
                                                          acc[mt_], 0, 0, 0);\
    }                                                                        \
    int col_ = (nb_) * 16 + m;                                               \
    _Pragma("unroll")                                                        \
    for (int mt_ = 0; mt_ < 2; ++mt_)                                        \
      _Pragma("unroll")                                                      \
      for (int r_ = 0; r_ < 4; ++r_) {                                       \
        float s_ = fmaf(-2.0f, acc[mt_][r_], ev_);                           \
        if (s_ < m1[mt_][r_]) {                                              \
          m2[mt_][r_] = m1[mt_][r_]; m1[mt_][r_] = s_; i1[mt_][r_] = col_;   \
        } else if (s_ < m2[mt_][r_]) { m2[mt_][r_] = s_; }                   \
      }                                                                      \
  }

__global__ __launch_bounds__(256, 2) void vq_argmin_mfma(
        const float* __restrict__ x, const uint4* __restrict__ Bh,
        const float* __restrict__ e2,
        int* __restrict__ idx, int* __restrict__ counts,
        int* __restrict__ refine_rows, int* __restrict__ refine_cnt) {

    __shared__ int hist[KCODE];   // 4 KB (epilogue only)

    const int tid = threadIdx.x;
    const int w = tid >> 6, l = tid & 63;
    const int m = l & 15, q = l >> 4;
    const int rw = blockIdx.x * 128 + w * 32;

    // B prefetch prologue (in flight while the A-phase loads/converts)
    uint4 bA[4], bB[4];
    float evA, evB;
    LOADB(bA, evA, 0);
    LOADB(bB, evB, 1);

    // ---------- A-phase: f16 A-fragments straight from global ----------
    // lane (m,q) of m-tile mt holds x[rw+mt*16+m][t*32 + q*8 + j], j=0..7
    const float4* x4 = (const float4*)x;
    half8 ah[2][4];                 // [m-tile][k-tile]
    #pragma unroll
    for (int mt = 0; mt < 2; ++mt) {
        int row = rw + mt * 16 + m;
        #pragma unroll
        for (int t = 0; t < 4; ++t) {
            int c4 = t * 8 + q * 2;
            float4 va = x4[(size_t)row * 32 + c4];
            float4 vb = x4[(size_t)row * 32 + c4 + 1];
            half8 hh;
            hh[0] = (_Float16)va.x; hh[1] = (_Float16)va.y;
            hh[2] = (_Float16)va.z; hh[3] = (_Float16)va.w;
            hh[4] = (_Float16)vb.x; hh[5] = (_Float16)vb.y;
            hh[6] = (_Float16)vb.z; hh[7] = (_Float16)vb.w;
            ah[mt][t] = hh;
        }
    }

    float m1[2][4], m2[2][4];
    int i1[2][4];
    #pragma unroll
    for (int a = 0; a < 2; ++a)
        #pragma unroll
        for (int r = 0; r < 4; ++r) { m1[a][r] = FLT_MAX; m2[a][r] = FLT_MAX; i1[a][r] = 0; }

    // ---------- K-loop over 64 n-blocks of 16 codes, barrier-free ----------
    for (int nb = 0; nb < 64; nb += 2) {
        COMPUTE_NB(nb, bA, evA);
        { int p = (nb + 2 <= 63) ? nb + 2 : 62; LOADB(bA, evA, p); }
        COMPUTE_NB(nb + 1, bB, evB);
        { int p = (nb + 3 <= 63) ? nb + 3 : 63; LOADB(bB, evB, p); }
    }

    // ---------- merge across the 16 lanes of each quad ----------
    #pragma unroll
    for (int mt = 0; mt < 2; ++mt)
        #pragma unroll
        for (int r = 0; r < 4; ++r) {
            float a1 = m1[mt][r], a2 = m2[mt][r];
            int ai = i1[mt][r];
            #pragma unroll
            for (int off = 1; off < 16; off <<= 1) {
                float o1 = __shfl_xor(a1, off, 64);
                float o2 = __shfl_xor(a2, off, 64);
                int oi = __shfl_xor(ai, off, 64);
                float hi = fmaxf(a1, o1);
                float n2 = fminf(fminf(a2, o2), hi);
                bool take = (o1 < a1) || (o1 == a1 && oi < ai);  // first-index ties
                a1 = fminf(a1, o1);
                ai = take ? oi : ai;
                a2 = n2;
            }
            m1[mt][r] = a1; m2[mt][r] = a2; i1[mt][r] = ai;
        }

    // ---------- write idx, LDS-aggregated histogram, refine list ----------
    for (int i = tid; i < KCODE; i += 256) hist[i] = 0;
    __syncthreads();
    if (m == 0) {   // 4 representative lanes per wave (one per quad)
        #pragma unroll
        for (int mt = 0; mt < 2; ++mt)
            #pragma unroll
            for (int r = 0; r < 4; ++r) {
                int row = rw + mt * 16 + q * 4 + r;
                int bi = i1[mt][r];
                idx[row] = bi;
                atomicAdd(&hist[bi], 1);
                if (!(m2[mt][r] - m1[mt][r] > MARGIN)) {
                    int pos = atomicAdd(refine_cnt, 1);
                    refine_rows[pos] = row;
                }
            }
    }
    __syncthreads();
    for (int i = tid; i < KCODE; i += 256) {
        int h = hist[i];
        if (h) atomicAdd(&counts[i], h);
    }
}

// ============================================================
// Exact re-resolution of ambiguous rows, fp32 expanded form (same arithmetic
// structure as the reference: e2 - 2*x.e, error ~1e-5). 16 rows per batch;
// E loads batched 16-wide so 16 independent loads are in flight over 256
// FMAs. Grid 512: one sweep covers 8192 rows.
#define RROWS 16
__global__ __launch_bounds__(256, 2) void vq_refine(
        const float* __restrict__ x, const float* __restrict__ E,
        const float* __restrict__ e2,
        const int* __restrict__ refine_rows, const int* __restrict__ refine_cnt,
        int* __restrict__ idx, int* __restrict__ counts) {
    __shared__ float xs[RROWS][DIMD];   // 8 KB
    __shared__ float rv[4][RROWS];
    __shared__ int   ri_[4][RROWS];
    const int cnt = *refine_cnt;
    const int tid = threadIdx.x;
    const int wave = tid >> 6, lane = tid & 63;

    for (int bb = blockIdx.x * RROWS; bb < cnt; bb += gridDim.x * RROWS) {
        __syncthreads();   // previous iteration done with LDS
        for (int i = tid; i < RROWS * DIMD; i += 256) {
            int r = i >> 7, d = i & 127;
            int wl = bb + r;
            if (wl >= cnt) wl = cnt - 1;        // clamp (dup compute, guarded write)
            xs[r][d] = x[(size_t)refine_rows[wl] * DIMD + d];
        }
        __syncthreads();

        float best[RROWS]; int bi[RROWS];
        #pragma unroll
        for (int r = 0; r < RROWS; ++r) { best[r] = FLT_MAX; bi[r] = 0; }

        for (int kc = 0; kc < KCODE / 256; ++kc) {
            int k = kc * 256 + tid;
            float acc[RROWS];
            #pragma unroll
            for (int r = 0; r < RROWS; ++r) acc[r] = 0.f;
            for (int d0 = 0; d0 < DIMD; d0 += 16) {
                float ev[16];
                #pragma unroll
                for (int dd = 0; dd < 16; ++dd)
                    ev[dd] = E[(size_t)(d0 + dd) * KCODE + k];   // 16 loads in flight
                #pragma unroll
                for (int dd = 0; dd < 16; ++dd)
                    #pragma unroll
                    for (int r = 0; r < RROWS; ++r)
                        acc[r] = fmaf(xs[r][d0 + dd], ev[dd], acc[r]);
            }
            float e2k = e2[k];
            #pragma unroll
            for (int r = 0; r < RROWS; ++r) {
                float s = fmaf(-2.0f, acc[r], e2k);
                if (s < best[r]) { best[r] = s; bi[r] = k; }   // k ascending: first-min
            }
        }

        // reduce over 64 lanes, then 4 waves; ties -> lowest index
        #pragma unroll
        for (int r = 0; r < RROWS; ++r) {
            float b = best[r]; int j = bi[r];
            #pragma unroll
            for (int off = 1; off < 64; off <<= 1) {
                float ob = __shfl_xor(b, off, 64);
                int oj = __shfl_xor(j, off, 64);
                if (ob < b || (ob == b && oj < j)) { b = ob; j = oj; }
            }
            if (lane == 0) { rv[wave][r] = b; ri_[wave][r] = j; }
        }
        __syncthreads();
        if (tid < RROWS) {
            int r = tid;
            float b = rv[0][r]; int j = ri_[0][r];
            #pragma unroll
            for (int wv = 1; wv < 4; ++wv) {
                float ob = rv[wv][r]; int oj = ri_[wv][r];
                if (ob < b || (ob == b && oj < j)) { b = ob; j = oj; }
            }
            int wl = bb + r;
            if (wl < cnt) {
                int n = refine_rows[wl];
                int oldk = idx[n];
                if (j != oldk) {
                    idx[n] = j;
                    atomicSub(&counts[oldk], 1);
                    atomicAdd(&counts[j], 1);
                }
            }
        }
    }
}

// ============================================================
__global__ void vq_scan(const int* __restrict__ counts, int* __restrict__ cursor) {
    __shared__ int s[KCODE];
    int t = threadIdx.x;
    int c = counts[t];
    s[t] = c;
    __syncthreads();
    for (int off = 1; off < KCODE; off <<= 1) {
        int v = (t >= off) ? s[t - off] : 0;
        __syncthreads();
        s[t] += v;
        __syncthreads();
    }
    cursor[t] = s[t] - c;
}

// LDS-aggregated bucket fill (kills same-address global atomic chains)
__global__ void vq_fill(const int* __restrict__ idx, int* __restrict__ cursor,
                        int* __restrict__ rowlist) {
    __shared__ int hcnt[KCODE];
    __shared__ int hbase[KCODE];
    int tid = threadIdx.x;
    for (int i = tid; i < KCODE; i += 256) hcnt[i] = 0;
    __syncthreads();
    int n = blockIdx.x * 256 + tid;
    int k = idx[n];
    int lrank = atomicAdd(&hcnt[k], 1);
    __syncthreads();
    for (int i = tid; i < KCODE; i += 256) {
        int h = hcnt[i];
        if (h) hbase[i] = atomicAdd(&cursor[i], h);
    }
    __syncthreads();
    rowlist[hbase[k] + lrank] = n;
}

// Balanced segment-sum: each block scans 128 rowlist entries (sorted by code),
// accumulates per-thread-d partials, flushes at code boundaries via atomics.
__global__ void vq_chunksum(const float* __restrict__ x,
                            const int* __restrict__ rowlist,
                            const int* __restrict__ idx,
                            float* __restrict__ sums) {
    __shared__ int rl[128];
    __shared__ int kk[128];
    int tid = threadIdx.x;   // 128 threads, tid == d
    int base = blockIdx.x * 128;
    int r = rowlist[base + tid];
    rl[tid] = r;
    kk[tid] = idx[r];
    __syncthreads();
    float s = 0.f;
    int kprev = kk[0];
    #pragma unroll 4
    for (int j = 0; j < 128; ++j) {
        int kj = kk[j];
        if (kj != kprev) {
            atomicAdd(&sums[(size_t)kprev * DIMD + tid], s);
            s = 0.f;
            kprev = kj;
        }
        s += x[(size_t)rl[j] * DIMD + tid];
    }
    atomicAdd(&sums[(size_t)kprev * DIMD + tid], s);
}

// q_st = x + (quantized - x) (replicating reference fp32 rounding) + loss.
// Per-block partial scattered over 256 slots (round-4 lesson: 16384 blocks
// atomic-adding ONE address serialized at L2 for ~250 us).
__global__ void vq_quantize_loss(const float* __restrict__ x,
                                 const float* __restrict__ ET,
                                 const int* __restrict__ idx,
                                 float* __restrict__ out,
                                 float* __restrict__ lpart) {
    size_t gid = (size_t)blockIdx.x * 256 + threadIdx.x;
    size_t base = gid * 4;
    int n = (int)(base >> 7);
    int d = (int)(base & 127);
    int k = idx[n];
    float4 xv = *(const float4*)(x + base);
    float4 qv = *(const float4*)(ET + (size_t)k * DIMD + d);
    float t0 = qv.x - xv.x, t1 = qv.y - xv.y, t2 = qv.z - xv.z, t3 = qv.w - xv.w;
    float4 o;
    o.x = xv.x + t0; o.y = xv.y + t1; o.z = xv.z + t2; o.w = xv.w + t3;
    *(float4*)(out + OUT_QST + base) = o;
    float partial = t0 * t0 + t1 * t1 + t2 * t2 + t3 * t3;
    #pragma unroll
    for (int off = 32; off > 0; off >>= 1)
        partial += __shfl_down(partial, off);
    __shared__ float wsum[4];
    int wave = threadIdx.x >> 6;
    if ((threadIdx.x & 63) == 0) wsum[wave] = partial;
    __syncthreads();
    if (threadIdx.x == 0)
        atomicAdd(&lpart[blockIdx.x & 255], wsum[0] + wsum[1] + wsum[2] + wsum[3]);
}

// EMA outputs from sums + counts; block 0 also reduces the 256 loss slots
// (launched after vq_quantize_loss).
__global__ void vq_finalize_emb(const int* __restrict__ counts,
                                const float* __restrict__ sums,
                                const float* __restrict__ emc,
                                const float* __restrict__ es,
                                const float* __restrict__ lpart,
                                float* __restrict__ out) {
    int gid = blockIdx.x * 256 + threadIdx.x;   // 131072
    int k = gid & (KCODE - 1), d = gid >> 10;
    float cnt = (float)counts[k];
    float ecn = fmaf(0.85f, cnt, 0.15f * emc[k]);
    float esn = fmaf(0.85f, sums[(size_t)k * DIMD + d], 0.15f * es[(size_t)d * KCODE + k]);
    out[OUT_ES + (size_t)d * KCODE + k] = esn;
    out[OUT_EMB + (size_t)d * KCODE + k] = esn / fmaxf(ecn, 1e-5f);
    if (d == 0) out[OUT_CNT + k] = ecn;
    if (blockIdx.x == 0) {
        float v = lpart[threadIdx.x];   // 256 slots, 256 threads
        #pragma unroll
        for (int off = 32; off > 0; off >>= 1)
            v += __shfl_down(v, off);
        __shared__ float ws4[4];
        if ((threadIdx.x & 63) == 0) ws4[threadIdx.x >> 6] = v;
        __syncthreads();
        if (threadIdx.x == 0)
            out[OUT_LOSS] = (ws4[0] + ws4[1] + ws4[2] + ws4[3]) /
                            ((float)NROWS * (float)DIMD);  // BETA = 1
    }
}

// ============================================================
extern "C" void kernel_launch(void* const* d_in, const int* in_sizes, int n_in,
                              void* d_out, int out_size, void* d_ws, size_t ws_size,
                              hipStream_t stream) {
    const float* x   = (const float*)d_in[0];
    const float* E   = (const float*)d_in[1];
    const float* emc = (const float*)d_in[2];
    const float* es  = (const float*)d_in[3];
    float* out = (float*)d_out;
    char* ws = (char*)d_ws;

    int*    refine_cnt  = (int*)(ws + WS_REFINE_CNT);
    int*    counts      = (int*)(ws + WS_COUNTS);
    float*  sums        = (float*)(ws + WS_SUMS);
    float*  lpart       = (float*)(ws + WS_LPART);
    int*    cursor      = (int*)(ws + WS_CURSOR);
    float*  e2          = (float*)(ws + WS_E2);
    float*  ET          = (float*)(ws + WS_ET);
    uint4*  Bh          = (uint4*)(ws + WS_BHI);
    int*    idx         = (int*)(ws + WS_IDX);
    int*    rowlist     = (int*)(ws + WS_ROWLIST);
    int*    refine_rows = (int*)(ws + WS_REFINE);

    // zero: refine counter, counts, sums, loss slots, cursor, e2
    hipMemsetAsync(ws, 0, WS_ZERO_BYTES, stream);

    vq_prep<<<64, 256, 0, stream>>>(E, Bh, ET, e2);
    vq_argmin_mfma<<<NROWS / 128, 256, 0, stream>>>(x, Bh, e2, idx, counts,
                                                    refine_rows, refine_cnt);
    vq_refine<<<512, 256, 0, stream>>>(x, E, e2, refine_rows, refine_cnt, idx, counts);
    vq_scan<<<1, KCODE, 0, stream>>>(counts, cursor);
    vq_fill<<<NROWS / 256, 256, 0, stream>>>(idx, cursor, rowlist);
    vq_chunksum<<<NROWS / 128, 128, 0, stream>>>(x, rowlist, idx, sums);
    vq_quantize_loss<<<(NROWS * (size_t)DIMD) / (256 * 4), 256, 0, stream>>>(x, ET, idx, out, lpart);
    vq_finalize_emb<<<(DIMD * KCODE) / 256, 256, 0, stream>>>(counts, sums, emc, es, lpart, out);
}